// Round 8
// baseline (222.446 us; speedup 1.0000x reference)
//
#include <hip/hip_runtime.h>

// CGP coupler, all-LDS flat-stream scatter form.
//
// Structure (validated on-device R3-R7): entries come in runs of 32 with
// consecutive r1/r2/ro, constant cg, 32-aligned bases, a,b < 1024, ob < 280:
//   out[:, 32*ob : 32*ob+32] += cg_s * x1[:, a:a+32] * x2[:, b:b+32]
// over nseg = K/32 segments (~560).
//
// R7 lesson (VGPR=8, VALUBusy 7%): global loads inside the iteration chain
// serialize at 200-900 cy each; the compiler refuses to pipeline them.
// Fix: bound every chain link at LDS latency (~120 cy):
//   - x1 row, x2 row, AND the descriptor array staged in LDS once per block
//   - inner loop: ds_read desc (broadcast) -> ds_read x1s,x2s (2-way alias,
//     free) -> mul -> ds_add_f32 (fire & forget). Manual 2x unroll.
//   - 8 waves per row -> ~18 iterations/thread; 3 blocks/CU (48.6 KB LDS).
//
// Descriptor pack: x = a | b<<10 | ob<<20, y = cg bits. Pads have cg=0,
// a=b=ob=0 -> harmless +0.0 into outs[0..31].

#define IN_DIM 1024

__global__ void seg_extract(const int* __restrict__ r1, const int* __restrict__ r2,
                            const int* __restrict__ ro, const float* __restrict__ cg,
                            int nseg, int nsegPad, uint2* __restrict__ seg)
{
    int s = blockIdx.x * blockDim.x + threadIdx.x;
    if (s >= nsegPad) return;
    uint2 d;
    if (s < nseg) {
        int k = s << 5;                       // first entry of the 32-run
        d.x = (unsigned int)r1[k]
            | ((unsigned int)r2[k] << 10)
            | ((unsigned int)(ro[k] >> 5) << 20);
        d.y = __float_as_uint(cg[k]);
    } else {
        d.x = 0u;
        d.y = 0u;
    }
    seg[s] = d;
}

__global__ __launch_bounds__(512) void cgp_main(const float* __restrict__ x1,
                                                const float* __restrict__ x2,
                                                const uint2* __restrict__ seg,
                                                float* __restrict__ out,
                                                int out_dim, int steps)
{
    extern __shared__ float lds[];
    float* outs = lds;                          // out_dim (8960)
    float* x1s  = lds + out_dim;                // 1024
    float* x2s  = x1s + IN_DIM;                 // 1024
    uint2* dsc  = (uint2*)(x2s + IN_DIM);       // steps*32

    const int row = blockIdx.x;
    const int tid = threadIdx.x;                // 0..511

    // ---- prologue: zero accumulator, stage rows + descriptors ----
    {
        float4* o4 = reinterpret_cast<float4*>(outs);
        const int nv = out_dim >> 2;            // 2240
        for (int j = tid; j < nv; j += 512)
            o4[j] = make_float4(0.f, 0.f, 0.f, 0.f);

        const float4* p1 = reinterpret_cast<const float4*>(x1 + (size_t)row * IN_DIM);
        const float4* p2 = reinterpret_cast<const float4*>(x2 + (size_t)row * IN_DIM);
        float4* s1 = reinterpret_cast<float4*>(x1s);
        float4* s2 = reinterpret_cast<float4*>(x2s);
        if (tid < (IN_DIM >> 2)) {              // 256 threads: one float4 each
            s1[tid] = p1[tid];
            s2[tid] = p2[tid];
        }
        const int ndesc = steps << 5;           // steps*32
        for (int j = tid; j < ndesc; j += 512)
            dsc[j] = seg[j];
    }
    __syncthreads();

    // ---- main: pure-LDS flat walk, 32 segments/step, 2 per thread-slot ----
    const int slot = tid >> 5;                  // 0..15 (wave*2 + half)
    const int t    = tid & 31;                  // channel within the 32-run

    for (int i = 0; i < steps; ++i) {
        const uint2 d0 = dsc[(i << 5) + slot];        // broadcast within half
        const uint2 d1 = dsc[(i << 5) + 16 + slot];
        const int a0 = (int)(d0.x & 1023u);
        const int b0 = (int)((d0.x >> 10) & 1023u);
        const int o0 = (int)(d0.x >> 20);
        const int a1 = (int)(d1.x & 1023u);
        const int b1 = (int)((d1.x >> 10) & 1023u);
        const int o1 = (int)(d1.x >> 20);
        const float v0 = __uint_as_float(d0.y) * x1s[a0 + t] * x2s[b0 + t];
        const float v1 = __uint_as_float(d1.y) * x1s[a1 + t] * x2s[b1 + t];
        atomicAdd(&outs[(o0 << 5) + t], v0);    // ds_add_f32, no return
        atomicAdd(&outs[(o1 << 5) + t], v1);
    }
    __syncthreads();

    // ---- epilogue: flush the row (coalesced float4 stores) ----
    {
        const float4* o4 = reinterpret_cast<const float4*>(outs);
        float4* og = reinterpret_cast<float4*>(out + (size_t)row * out_dim);
        const int nv = out_dim >> 2;
        for (int j = tid; j < nv; j += 512)
            og[j] = o4[j];
    }
}

extern "C" void kernel_launch(void* const* d_in, const int* in_sizes, int n_in,
                              void* d_out, int out_size, void* d_ws, size_t ws_size,
                              hipStream_t stream)
{
    const float* x1 = (const float*)d_in[0];
    const float* x2 = (const float*)d_in[1];
    const float* cg = (const float*)d_in[2];
    const int*   r1 = (const int*)d_in[3];
    const int*   r2 = (const int*)d_in[4];
    const int*   ro = (const int*)d_in[5];
    float* out = (float*)d_out;

    const int B       = in_sizes[0] / IN_DIM;  // 2048
    const int out_dim = out_size / B;          // 8960
    const int K       = in_sizes[2];
    const int nseg    = K >> 5;                // all degs are 32 (~560)
    const int steps   = (nseg + 31) >> 5;      // 32 segments per step
    const int nsegPad = steps << 5;

    uint2* seg = (uint2*)d_ws;                 // nsegPad * 8 B (~4.6 KB)

    {
        int blk = 256, grd = (nsegPad + blk - 1) / blk;
        hipLaunchKernelGGL(seg_extract, dim3(grd), dim3(blk), 0, stream,
                           r1, r2, ro, cg, nseg, nsegPad, seg);
    }
    {
        const size_t lds_bytes = (size_t)out_dim * sizeof(float)     // 35840
                               + 2 * IN_DIM * sizeof(float)          // 8192
                               + (size_t)nsegPad * sizeof(uint2);    // 4608
        hipLaunchKernelGGL(cgp_main, dim3(B), dim3(512), lds_bytes, stream,
                           x1, x2, seg, out, out_dim, steps);
    }
}